// Round 8
// baseline (192.764 us; speedup 1.0000x reference)
//
#include <hip/hip_runtime.h>
#include <hip/hip_bf16.h>

// ---------------------------------------------------------------------------
// Hierarchical_CBlock: 15 pairwise GEMMs [16384x512]@[512x256] + bias + tanh
// + NAS mask, then final GEMM [16384x3840]@[3840x256] + bias.
// fp32 interfaces; bf16 internal MFMA (absmax 7.8e-3 vs 2.31e-2 threshold).
// R8 counters: fused ~56-59us, MfmaUtil 3.9%, VALU 10%, Occ 22% (1 blk/CU).
// R9/R10: counted-vmcnt pipelining x2 => NEUTRAL. In-block latency hiding is
//   falsified on this structure; ~1500 cyc/step idle persists.
// R13: occupancy pivot, atomics-free. Pairs split by rank parity across
//   blockIdx.y in {0,1}; each half runs the verified R7 inner loop on its
//   subset and stores a RAW fp32 partial to workspace. combine_out kernel
//   adds part0+part1+b_final. LDS 75.8KiB/block -> 2 blocks/CU (151.6<160),
//   launch_bounds(512,4), VGPR~64 => 16 waves/CU. Two independent barrier
//   domains per CU hide each other's staging drains (m114 mechanism).
// R14: identical resubmission of R13 (GPUAcquisitionTimeout infra failure).
// ---------------------------------------------------------------------------

typedef unsigned short u16;
typedef __bf16 bf16x8 __attribute__((ext_vector_type(8)));
typedef float f32x4 __attribute__((ext_vector_type(4)));

#define BS 16384      // B*S tokens
#define EMB 256
#define PAIRS 15
#define XRS 40        // ldsX row stride in bf16 (80B: 16B-aligned frags)

__constant__ int c_pi[PAIRS] = {0,0,0,0,0,1,1,1,1,2,2,2,3,3,4};
__constant__ int c_pj[PAIRS] = {1,2,3,4,5,2,3,4,5,3,4,5,4,5,5};

__device__ __forceinline__ u16 f2bf_u(float x) {
    __bf16 b = (__bf16)x;   // RTN
    return __builtin_bit_cast(u16, b);
}

// ============== merged transpose + fp32->bf16 convert ======================
__global__ __launch_bounds__(256) void transpose_cvt2(
    const float* __restrict__ Wp, const float* __restrict__ Wf,
    u16* __restrict__ Wp_t, u16* __restrict__ Wf_t)
{
    __shared__ float t[32][33];
    const int z = blockIdx.z;
    const float* in;
    u16* out;
    int R;
    if (z < PAIRS) { R = 512;  in = Wp + (size_t)z * 512 * 256; out = Wp_t + (size_t)z * 256 * 512; }
    else           { R = 3840; in = Wf;                          out = Wf_t; }
    const int r0 = blockIdx.x * 32;
    if (r0 >= R) return;                    // block-uniform early exit
    const int c0 = blockIdx.y * 32;
    const int tr = threadIdx.x >> 5;
    const int tc = threadIdx.x & 31;
#pragma unroll
    for (int pass = 0; pass < 4; ++pass)
        t[pass * 8 + tr][tc] = in[(size_t)(r0 + pass * 8 + tr) * 256 + c0 + tc];
    __syncthreads();
#pragma unroll
    for (int pass = 0; pass < 4; ++pass)
        out[(size_t)(c0 + pass * 8 + tr) * R + r0 + tc] = f2bf_u(t[tc][pass * 8 + tr]);
}

// ============================ fused MFMA path ==============================

// Stage a 32k x 256n bf16 weight tile (16 KB) into LDS as 1024 16B chunks.
__device__ __forceinline__ void stage_tile(const u16* gsrc, int row_stride_us,
                                           int col_off_us, u16* lds_base, int tid) {
    int wave = tid >> 6;
#pragma unroll
    for (int r = 0; r < 2; ++r) {
        int c  = r * 512 + tid;
        int n  = c & 255;
        int kb = c >> 8;
        const u16* g = gsrc + (size_t)n * row_stride_us + col_off_us + kb * 8;
        u16* l = lds_base + (size_t)(r * 512 + wave * 64) * 8;  // wave-uniform
        __builtin_amdgcn_global_load_lds(
            (const __attribute__((address_space(1))) void*)g,
            (__attribute__((address_space(3))) void*)l,
            16, 0, 0);
    }
}

// Stage a 64-token x 32-k X-slice as bf16 into ldsX (stride XRS).
__device__ __forceinline__ void stage_x(const float* fsrc, int t0, int col0,
                                        u16* ldsx, int tid) {
    const int row = tid >> 3;
    const int cg  = (tid & 7) * 4;
    f32x4 v = *(const f32x4*)(fsrc + (size_t)(t0 + row) * EMB + col0 + cg);
    ushort4 o;
    o.x = f2bf_u(v[0]); o.y = f2bf_u(v[1]); o.z = f2bf_u(v[2]); o.w = f2bf_u(v[3]);
    *(ushort4*)(ldsx + row * XRS + cg) = o;   // 8B store, 8B-aligned
}

__global__ __launch_bounds__(512, 4) void fused_cblock(
    const float* __restrict__ feats,   // [6][16384][256] fp32
    const u16* __restrict__ Wp_t,      // [15][256][512] bf16 (transposed)
    const float* __restrict__ b_pair,  // [15][256] fp32
    const u16* __restrict__ Wf_t,      // [256][3840] bf16 (transposed)
    const int* __restrict__ NAS,       // [6]
    float* __restrict__ part)          // [2][16384][256] fp32 raw partials
{
    __shared__ u16 lds_b[2][8192];     // 2 x 16KB weight-tile double buffer
    __shared__ u16 lds_h[64 * 264];    // h tile bf16, stride 264
    __shared__ u16 lds_x[2][64 * XRS]; // 2 x 5KB X-tile double buffer

    const int tid  = threadIdx.x;
    const int lane = tid & 63;
    const int wave = tid >> 6;
    const int wm   = wave & 1;         // 32-token slab
    const int wn   = wave >> 1;        // 64-col group (0..3)
    const int quad = lane >> 4;
    const int l16  = lane & 15;
    const int t0   = blockIdx.x * 64;
    const int half = blockIdx.y;       // pair-parity half (0 or 1)
    float* my_part = part + (size_t)half * BS * EMB;

    int nasv[6];
#pragma unroll
    for (int f = 0; f < 6; ++f) nasv[f] = (f < 2) ? 1 : (NAS[f] != 0 ? 1 : 0);
    // active pairs of THIS half: rank parity over the active-pair sequence
    int mymask = 0, rank = 0;
#pragma unroll
    for (int p = 0; p < PAIRS; ++p)
        if (nasv[c_pi[p]] & nasv[c_pj[p]]) {
            if ((rank & 1) == half) mymask |= (1 << p);
            ++rank;
        }
    if (mymask == 0) {                 // <2 active pairs: half 1 writes zeros
        for (int i = tid; i < 64 * EMB; i += 512)
            my_part[(size_t)t0 * EMB + i] = 0.f;
        return;                        // block-uniform, before any barrier
    }

    // Entry prefetch: this half's first active pair.
    const int p0 = __builtin_ctz(mymask);
    stage_tile(Wp_t + (size_t)p0 * 256 * 512, 512, 0, lds_b[0], tid);
    stage_x(feats + (size_t)c_pi[p0] * BS * EMB, t0, 0, lds_x[0], tid);

    const f32x4 fzero = {0.f, 0.f, 0.f, 0.f};
    f32x4 acc2[8];                     // [mt*4+nt]
#pragma unroll
    for (int i = 0; i < 8; ++i) acc2[i] = fzero;

    __syncthreads();                    // drain entry prefetch (vm + lds)

    for (int p = 0; p < PAIRS; ++p) {
        if (!((mymask >> p) & 1)) continue;
        const int fi = c_pi[p], fj = c_pj[p];
        const u16* WpT = Wp_t + (size_t)p * 256 * 512;
        const int rest  = mymask >> (p + 1);
        const int pnext = rest ? (p + 1 + __builtin_ctz(rest)) : -1;

        // -------- GEMM1: h[64x256] = tanh(X[64x512] @ Wp + b) --------------
        f32x4 acc1[8];
#pragma unroll
        for (int i = 0; i < 8; ++i) acc1[i] = fzero;

        for (int ks = 0; ks < 16; ++ks) {
            const int cur = ks & 1;
            if (ks < 15) {
                stage_tile(WpT, 512, (ks + 1) * 32, lds_b[1 - cur], tid);
                stage_x(feats + (size_t)((ks + 1 < 8) ? fi : fj) * BS * EMB,
                        t0, ((ks + 1) & 7) * 32, lds_x[1 - cur], tid);
            } else {
                stage_tile(Wf_t, 3840, p * 256, lds_b[1 - cur], tid); // GEMM2 k0
            }
            bf16x8 a0 = *(const bf16x8*)(&lds_x[cur][(wm * 32 + l16) * XRS + quad * 8]);
            bf16x8 a1 = *(const bf16x8*)(&lds_x[cur][(wm * 32 + 16 + l16) * XRS + quad * 8]);
#pragma unroll
            for (int nt = 0; nt < 4; ++nt) {
                const int n = wn * 64 + nt * 16 + l16;
                bf16x8 b = *(const bf16x8*)(&lds_b[cur][(quad * 256 + n) * 8]);
                acc1[nt]     = __builtin_amdgcn_mfma_f32_16x16x32_bf16(a0, b, acc1[nt],     0, 0, 0);
                acc1[4 + nt] = __builtin_amdgcn_mfma_f32_16x16x32_bf16(a1, b, acc1[4 + nt], 0, 0, 0);
            }
            __syncthreads();
        }

        // tanh + bias (fp32), h -> LDS bf16
#pragma unroll
        for (int mt = 0; mt < 2; ++mt)
#pragma unroll
        for (int nt = 0; nt < 4; ++nt) {
            const int n = wn * 64 + nt * 16 + l16;
            const float bias = b_pair[p * 256 + n];
#pragma unroll
            for (int r = 0; r < 4; ++r) {
                const int row = wm * 32 + mt * 16 + quad * 4 + r;  // C/D: row=quad*4+reg
                lds_h[row * 264 + n] = f2bf_u(tanhf(acc1[mt * 4 + nt][r] + bias));
            }
        }
        __syncthreads();   // publish lds_h (Wf k0 drained at ks=15 barrier)

        // -------- GEMM2: acc2 += h[64x256] @ Wf_p[256x256] ------------------
        for (int ks = 0; ks < 8; ++ks) {
            const int cur = ks & 1;
            if (ks < 7)
                stage_tile(Wf_t, 3840, p * 256 + (ks + 1) * 32, lds_b[1 - cur], tid);
            else if (pnext >= 0)   // prefetch next pair's Wp k0 -> buf0
                stage_tile(Wp_t + (size_t)pnext * 256 * 512, 512, 0, lds_b[1 - cur], tid);
            if (ks == 0 && pnext >= 0)  // prefetch next pair's X k0 -> xbuf0
                stage_x(feats + (size_t)c_pi[pnext] * BS * EMB, t0, 0, lds_x[0], tid);
            const int e0 = ks * 32 + quad * 8;
            bf16x8 a0 = *(const bf16x8*)(&lds_h[(wm * 32 + l16) * 264 + e0]);
            bf16x8 a1 = *(const bf16x8*)(&lds_h[(wm * 32 + 16 + l16) * 264 + e0]);
#pragma unroll
            for (int nt = 0; nt < 4; ++nt) {
                const int n = wn * 64 + nt * 16 + l16;
                bf16x8 b = *(const bf16x8*)(&lds_b[cur][(quad * 256 + n) * 8]);
                acc2[nt]     = __builtin_amdgcn_mfma_f32_16x16x32_bf16(a0, b, acc2[nt],     0, 0, 0);
                acc2[4 + nt] = __builtin_amdgcn_mfma_f32_16x16x32_bf16(a1, b, acc2[4 + nt], 0, 0, 0);
            }
            __syncthreads();
        }
    }

    // epilogue: raw partial store (bias added in combine_out)
#pragma unroll
    for (int mt = 0; mt < 2; ++mt)
#pragma unroll
    for (int nt = 0; nt < 4; ++nt) {
        const int n = wn * 64 + nt * 16 + l16;
#pragma unroll
        for (int r = 0; r < 4; ++r) {
            const int t = t0 + wm * 32 + mt * 16 + quad * 4 + r;
            my_part[(size_t)t * EMB + n] = acc2[mt * 4 + nt][r];
        }
    }
}

// out = part0 + part1 + b_final  (4M floats as 1M f32x4)
__global__ __launch_bounds__(256) void combine_out(
    const float* __restrict__ p0, const float* __restrict__ p1,
    const float* __restrict__ bf, float* __restrict__ out)
{
    const int i = blockIdx.x * 256 + threadIdx.x;       // f32x4 index
    f32x4 a = ((const f32x4*)p0)[i];
    f32x4 b = ((const f32x4*)p1)[i];
    f32x4 c = ((const f32x4*)bf)[i & 63];               // col group (i*4)%256
    f32x4 r;
#pragma unroll
    for (int k = 0; k < 4; ++k) r[k] = a[k] + b[k] + c[k];
    ((f32x4*)out)[i] = r;
}

// ================== exact fp32 VALU fallback (ws-free) =====================

#define TOK 4

__global__ __launch_bounds__(256) void fallback_cblock(
    const float* __restrict__ feats, const float* __restrict__ W_pair,
    const float* __restrict__ b_pair, const float* __restrict__ W_final,
    const float* __restrict__ b_final, const int* __restrict__ NAS,
    float* __restrict__ out)
{
    __shared__ float xs[TOK][6 * 256];
    __shared__ float hf[TOK][PAIRS * 256];

    const int n  = threadIdx.x;
    const int t0 = blockIdx.x * TOK;

#pragma unroll
    for (int tk = 0; tk < TOK; ++tk)
#pragma unroll
        for (int f = 0; f < 6; ++f)
            xs[tk][f * 256 + n] = feats[((size_t)f * BS + t0 + tk) * EMB + n];
    __syncthreads();

    int nasv[6];
#pragma unroll
    for (int f = 0; f < 6; ++f) nasv[f] = (f < 2) ? 1 : (NAS[f] != 0 ? 1 : 0);

    for (int p = 0; p < PAIRS; ++p) {
        const int fi = c_pi[p], fj = c_pj[p];
        if (!(nasv[fi] & nasv[fj])) {
#pragma unroll
            for (int tk = 0; tk < TOK; ++tk) hf[tk][p * 256 + n] = 0.f;
            continue;
        }
        float acc[TOK];
        const float bias = b_pair[p * 256 + n];
#pragma unroll
        for (int tk = 0; tk < TOK; ++tk) acc[tk] = bias;
        const float* Wp = W_pair + (size_t)p * 512 * 256;
#pragma unroll 4
        for (int k = 0; k < 512; ++k) {
            const float w = Wp[(size_t)k * 256 + n];
            const int xoff = ((k < 256) ? fi : fj) * 256 + (k & 255);
#pragma unroll
            for (int tk = 0; tk < TOK; ++tk) acc[tk] += xs[tk][xoff] * w;
        }
#pragma unroll
        for (int tk = 0; tk < TOK; ++tk)
            hf[tk][p * 256 + n] = tanhf(acc[tk]);
    }
    __syncthreads();

    float acc[TOK];
    const float bf = b_final[n];
#pragma unroll
    for (int tk = 0; tk < TOK; ++tk) acc[tk] = bf;
#pragma unroll 4
    for (int k = 0; k < PAIRS * 256; ++k) {
        const float w = W_final[(size_t)k * 256 + n];
#pragma unroll
        for (int tk = 0; tk < TOK; ++tk) acc[tk] += hf[tk][k] * w;
    }
#pragma unroll
    for (int tk = 0; tk < TOK; ++tk)
        out[(size_t)(t0 + tk) * EMB + n] = acc[tk];
}

// ===========================================================================

extern "C" void kernel_launch(void* const* d_in, const int* in_sizes, int n_in,
                              void* d_out, int out_size, void* d_ws, size_t ws_size,
                              hipStream_t stream) {
    const float* feats   = (const float*)d_in[0];
    const float* W_pair  = (const float*)d_in[1];
    const float* b_pair  = (const float*)d_in[2];
    const float* W_final = (const float*)d_in[3];
    const float* b_final = (const float*)d_in[4];
    const int*   NAS     = (const int*)d_in[5];

    const size_t w_bytes = ((size_t)PAIRS * 256 * 512 + (size_t)256 * 3840) * 2;
    const size_t needed  = w_bytes + (size_t)2 * BS * EMB * 4;

    if (ws_size >= needed) {
        u16*   Wp_t = (u16*)d_ws;                        // 15*256*512 bf16
        u16*   Wf_t = Wp_t + (size_t)PAIRS * 256 * 512;  // 256*3840 bf16
        float* part = (float*)((char*)d_ws + w_bytes);   // [2][16384][256] fp32
        transpose_cvt2<<<dim3(3840 / 32, 256 / 32, PAIRS + 1), 256, 0, stream>>>(
            W_pair, W_final, Wp_t, Wf_t);
        fused_cblock<<<dim3(BS / 64, 2), 512, 0, stream>>>(feats, Wp_t, b_pair,
                                                           Wf_t, NAS, part);
        combine_out<<<(BS * EMB / 4) / 256, 256, 0, stream>>>(
            part, part + (size_t)BS * EMB, b_final, (float*)d_out);
    } else {
        fallback_cblock<<<BS / TOK, 256, 0, stream>>>(feats, W_pair, b_pair,
                                                      W_final, b_final, NAS,
                                                      (float*)d_out);
    }
}

// Round 9
// 179.834 us; speedup vs baseline: 1.0719x; 1.0719x over previous
//
#include <hip/hip_runtime.h>
#include <hip/hip_bf16.h>

// ---------------------------------------------------------------------------
// Hierarchical_CBlock: 15 pairwise GEMMs [16384x512]@[512x256] + bias + tanh
// + NAS mask, then final GEMM [16384x3840]@[3840x256] + bias.
// fp32 interfaces; bf16 internal MFMA (absmax 7.8e-3 vs 2.31e-2 threshold).
// R8/R13: occupancy pivot (2 blocks/CU) dead twice: blocks don't co-reside,
//   split adds +13us combine traffic. REVERTED to single grid.
// R9/R10: counted-vmcnt NEUTRAL — post-audit: R10's vmcnt(2) barrier drained
//   x(s+2) (5 outstanding, not 3) => the HBM feature load was re-exposed
//   (~900cyc) EVERY step in every version. ~1950cyc/step = 900 (x stall)
//   + 300-400 (tile drain) + ~400 work.
// R15: remove x from the per-step path STRUCTURALLY. Whole-feature X panels
//   (64 tok x 256 emb bf16, 33KB) staged once per feature: 8 f32x4/thread
//   loaded into regs at a step boundary with ~8 ksteps of cover, written to
//   LDS 7 steps later (fj: G1 ks0->ks7; next pair fi: G2 ks0->ks7).
//   Per-step VMEM = weight tile only (L2-hot). Keeps the proven R7
//   __syncthreads double-buffer loop — one change axis.
//   LDS: 32KB tiles + 3x33KB (xA,xB,h) = 131KiB, 1 block/CU.
// ---------------------------------------------------------------------------

typedef unsigned short u16;
typedef __bf16 bf16x8 __attribute__((ext_vector_type(8)));
typedef float f32x4 __attribute__((ext_vector_type(4)));

#define BS 16384      // B*S tokens
#define EMB 256
#define PAIRS 15
#define XR 264        // row stride (u16) for lds_x/lds_h: 528B rows, 16B-aligned

__constant__ int c_pi[PAIRS] = {0,0,0,0,0,1,1,1,1,2,2,2,3,3,4};
__constant__ int c_pj[PAIRS] = {1,2,3,4,5,2,3,4,5,3,4,5,4,5,5};

__device__ __forceinline__ u16 f2bf_u(float x) {
    __bf16 b = (__bf16)x;   // RTN
    return __builtin_bit_cast(u16, b);
}

// ============== merged transpose + fp32->bf16 convert ======================
__global__ __launch_bounds__(256) void transpose_cvt2(
    const float* __restrict__ Wp, const float* __restrict__ Wf,
    u16* __restrict__ Wp_t, u16* __restrict__ Wf_t)
{
    __shared__ float t[32][33];
    const int z = blockIdx.z;
    const float* in;
    u16* out;
    int R;
    if (z < PAIRS) { R = 512;  in = Wp + (size_t)z * 512 * 256; out = Wp_t + (size_t)z * 256 * 512; }
    else           { R = 3840; in = Wf;                          out = Wf_t; }
    const int r0 = blockIdx.x * 32;
    if (r0 >= R) return;                    // block-uniform early exit
    const int c0 = blockIdx.y * 32;
    const int tr = threadIdx.x >> 5;
    const int tc = threadIdx.x & 31;
#pragma unroll
    for (int pass = 0; pass < 4; ++pass)
        t[pass * 8 + tr][tc] = in[(size_t)(r0 + pass * 8 + tr) * 256 + c0 + tc];
    __syncthreads();
#pragma unroll
    for (int pass = 0; pass < 4; ++pass)
        out[(size_t)(c0 + pass * 8 + tr) * R + r0 + tc] = f2bf_u(t[tc][pass * 8 + tr]);
}

// ============================ fused MFMA path ==============================

// Stage a 32k x 256n bf16 weight tile (16 KB) into LDS as 1024 16B chunks.
__device__ __forceinline__ void stage_tile(const u16* gsrc, int row_stride_us,
                                           int col_off_us, u16* lds_base, int tid) {
    int wave = tid >> 6;
#pragma unroll
    for (int r = 0; r < 2; ++r) {
        int c  = r * 512 + tid;
        int n  = c & 255;
        int kb = c >> 8;
        const u16* g = gsrc + (size_t)n * row_stride_us + col_off_us + kb * 8;
        u16* l = lds_base + (size_t)(r * 512 + wave * 64) * 8;  // wave-uniform
        __builtin_amdgcn_global_load_lds(
            (const __attribute__((address_space(1))) void*)g,
            (__attribute__((address_space(3))) void*)l,
            16, 0, 0);
    }
}

// Load a whole 64x256 feature panel for this block into 8 f32x4 registers.
// Thread t: row = t>>3, cols (t&7)*4 + 32*i, i=0..7 (128B coalesced groups).
__device__ __forceinline__ void xpanel_load(const float* fsrc, int t0,
                                            int xrow, int xcg, f32x4* xb) {
#pragma unroll
    for (int i = 0; i < 8; ++i)
        xb[i] = *(const f32x4*)(fsrc + (size_t)(t0 + xrow) * EMB + i * 32 + xcg);
}

// Convert + write the register panel into an LDS X panel (stride XR).
__device__ __forceinline__ void xpanel_write(const f32x4* xb, u16* ldsx,
                                             int xrow, int xcg) {
#pragma unroll
    for (int i = 0; i < 8; ++i) {
        ushort4 o;
        o.x = f2bf_u(xb[i][0]); o.y = f2bf_u(xb[i][1]);
        o.z = f2bf_u(xb[i][2]); o.w = f2bf_u(xb[i][3]);
        *(ushort4*)(&ldsx[xrow * XR + i * 32 + xcg]) = o;   // 8B store
    }
}

__global__ __launch_bounds__(512, 2) void fused_cblock(
    const float* __restrict__ feats,   // [6][16384][256] fp32
    const u16* __restrict__ Wp_t,      // [15][256][512] bf16 (transposed)
    const float* __restrict__ b_pair,  // [15][256] fp32
    const u16* __restrict__ Wf_t,      // [256][3840] bf16 (transposed)
    const float* __restrict__ b_final, // [256] fp32
    const int* __restrict__ NAS,       // [6]
    float* __restrict__ out)           // [16384][256] fp32
{
    __shared__ u16 lds_b[2][8192];     // 2 x 16KB weight-tile double buffer
    __shared__ u16 lds_xA[64 * XR];    // X panel (fi / next fi), 33KB
    __shared__ u16 lds_xB[64 * XR];    // X panel (fj), 33KB
    __shared__ u16 lds_h[64 * XR];     // h tile bf16, 33KB

    const int tid  = threadIdx.x;
    const int lane = tid & 63;
    const int wave = tid >> 6;
    const int wm   = wave & 1;         // 32-token slab
    const int wn   = wave >> 1;        // 64-col group (0..3)
    const int quad = lane >> 4;
    const int l16  = lane & 15;
    const int t0   = blockIdx.x * 64;
    const int xrow = tid >> 3;         // panel row (0..63)
    const int xcg  = (tid & 7) * 4;    // panel col group

    int nasv[6];
#pragma unroll
    for (int f = 0; f < 6; ++f) nasv[f] = (f < 2) ? 1 : (NAS[f] != 0 ? 1 : 0);
    int pmask = 0;
#pragma unroll
    for (int p = 0; p < PAIRS; ++p)
        if (nasv[c_pi[p]] & nasv[c_pj[p]]) pmask |= (1 << p);
    // pair 0 always active (features 0,1 forced on) => pmask bit0 == 1, fi=0.

    // ---- prologue: feature-0 panel -> xA, Wp0 k0 tile -> b0 ---------------
    f32x4 xb[8];
    xpanel_load(feats, t0, xrow, xcg, xb);
    stage_tile(Wp_t, 512, 0, lds_b[0], tid);
    xpanel_write(xb, lds_xA, xrow, xcg);    // auto-wait retires panel loads
    __syncthreads();                         // tile0 + xA ready

    const f32x4 fzero = {0.f, 0.f, 0.f, 0.f};
    f32x4 acc2[8];
#pragma unroll
    for (int i = 0; i < 8; ++i) acc2[i] = fzero;

    for (int p = 0; p < PAIRS; ++p) {
        if (!((pmask >> p) & 1)) continue;          // block-uniform
        const int fj = c_pj[p];
        const u16* WpT = Wp_t + (size_t)p * 256 * 512;
        const int rest  = pmask >> (p + 1);
        const int pnext = rest ? (p + 1 + __builtin_ctz(rest)) : -1;

        // -------- GEMM1: h[64x256] = tanh(X[64x512] @ Wp + b) --------------
        // Preconditions: lds_b[0] = Wp_p k0; lds_xA = X(fi) panel.
        f32x4 acc1[8];
#pragma unroll
        for (int i = 0; i < 8; ++i) acc1[i] = fzero;

        for (int ks = 0; ks < 16; ++ks) {
            const int cur = ks & 1;
            if (ks == 0)   // fj panel regs: ~7 ksteps of cover before write
                xpanel_load(feats + (size_t)fj * BS * EMB, t0, xrow, xcg, xb);
            if (ks < 15)
                stage_tile(WpT, 512, (ks + 1) * 32, lds_b[1 - cur], tid);
            else
                stage_tile(Wf_t, 3840, p * 256, lds_b[1 - cur], tid); // GEMM2 k0
            const u16* xs = (ks < 8) ? lds_xA : lds_xB;
            const int ko = (ks & 7) * 32 + quad * 8;
            bf16x8 a0 = *(const bf16x8*)(&xs[(wm * 32 + l16) * XR + ko]);
            bf16x8 a1 = *(const bf16x8*)(&xs[(wm * 32 + 16 + l16) * XR + ko]);
#pragma unroll
            for (int nt = 0; nt < 4; ++nt) {
                const int n = wn * 64 + nt * 16 + l16;
                bf16x8 b = *(const bf16x8*)(&lds_b[cur][(quad * 256 + n) * 8]);
                acc1[nt]     = __builtin_amdgcn_mfma_f32_16x16x32_bf16(a0, b, acc1[nt],     0, 0, 0);
                acc1[4 + nt] = __builtin_amdgcn_mfma_f32_16x16x32_bf16(a1, b, acc1[4 + nt], 0, 0, 0);
            }
            if (ks == 7)   // publish fj panel (reads of xB start at ks=8,
                xpanel_write(xb, lds_xB, xrow, xcg);  // after this barrier)
            __syncthreads();
        }

        // tanh + bias (fp32), h -> LDS bf16
#pragma unroll
        for (int mt = 0; mt < 2; ++mt)
#pragma unroll
        for (int nt = 0; nt < 4; ++nt) {
            const int n = wn * 64 + nt * 16 + l16;
            const float bias = b_pair[p * 256 + n];
#pragma unroll
            for (int r = 0; r < 4; ++r) {
                const int row = wm * 32 + mt * 16 + quad * 4 + r;  // C/D: row=quad*4+reg
                lds_h[row * XR + n] = f2bf_u(tanhf(acc1[mt * 4 + nt][r] + bias));
            }
        }
        __syncthreads();   // publish lds_h (Wf k0 drained at ks=15 barrier)

        // -------- GEMM2: acc2 += h[64x256] @ Wf_p[256x256] ------------------
        for (int ks = 0; ks < 8; ++ks) {
            const int cur = ks & 1;
            if (ks == 0 && pnext >= 0)   // next pair's fi panel into regs
                xpanel_load(feats + (size_t)c_pi[pnext] * BS * EMB, t0, xrow, xcg, xb);
            if (ks < 7)
                stage_tile(Wf_t, 3840, p * 256 + (ks + 1) * 32, lds_b[1 - cur], tid);
            else   // next pair's Wp k0 (dummy reload when last pair)
                stage_tile(Wp_t + (size_t)((pnext >= 0) ? pnext : p) * 256 * 512,
                           512, 0, lds_b[1 - cur], tid);
            const int e0 = ks * 32 + quad * 8;
            bf16x8 a0 = *(const bf16x8*)(&lds_h[(wm * 32 + l16) * XR + e0]);
            bf16x8 a1 = *(const bf16x8*)(&lds_h[(wm * 32 + 16 + l16) * XR + e0]);
#pragma unroll
            for (int nt = 0; nt < 4; ++nt) {
                const int n = wn * 64 + nt * 16 + l16;
                bf16x8 b = *(const bf16x8*)(&lds_b[cur][(quad * 256 + n) * 8]);
                acc2[nt]     = __builtin_amdgcn_mfma_f32_16x16x32_bf16(a0, b, acc2[nt],     0, 0, 0);
                acc2[4 + nt] = __builtin_amdgcn_mfma_f32_16x16x32_bf16(a1, b, acc2[4 + nt], 0, 0, 0);
            }
            if (ks == 7 && pnext >= 0)   // publish next fi panel into xA
                xpanel_write(xb, lds_xA, xrow, xcg);  // (xA reads resume next
            __syncthreads();                           //  pair G1 ks=0)
        }
    }

    // epilogue: + b_final, fp32 store
#pragma unroll
    for (int mt = 0; mt < 2; ++mt)
#pragma unroll
    for (int nt = 0; nt < 4; ++nt) {
        const int n = wn * 64 + nt * 16 + l16;
        const float bf = b_final[n];
#pragma unroll
        for (int r = 0; r < 4; ++r) {
            const int t = t0 + wm * 32 + mt * 16 + quad * 4 + r;
            out[(size_t)t * EMB + n] = acc2[mt * 4 + nt][r] + bf;
        }
    }
}

// ================== exact fp32 VALU fallback (ws-free) =====================

#define TOK 4

__global__ __launch_bounds__(256) void fallback_cblock(
    const float* __restrict__ feats, const float* __restrict__ W_pair,
    const float* __restrict__ b_pair, const float* __restrict__ W_final,
    const float* __restrict__ b_final, const int* __restrict__ NAS,
    float* __restrict__ out)
{
    __shared__ float xs[TOK][6 * 256];
    __shared__ float hf[TOK][PAIRS * 256];

    const int n  = threadIdx.x;
    const int t0 = blockIdx.x * TOK;

#pragma unroll
    for (int tk = 0; tk < TOK; ++tk)
#pragma unroll
        for (int f = 0; f < 6; ++f)
            xs[tk][f * 256 + n] = feats[((size_t)f * BS + t0 + tk) * EMB + n];
    __syncthreads();

    int nasv[6];
#pragma unroll
    for (int f = 0; f < 6; ++f) nasv[f] = (f < 2) ? 1 : (NAS[f] != 0 ? 1 : 0);

    for (int p = 0; p < PAIRS; ++p) {
        const int fi = c_pi[p], fj = c_pj[p];
        if (!(nasv[fi] & nasv[fj])) {
#pragma unroll
            for (int tk = 0; tk < TOK; ++tk) hf[tk][p * 256 + n] = 0.f;
            continue;
        }
        float acc[TOK];
        const float bias = b_pair[p * 256 + n];
#pragma unroll
        for (int tk = 0; tk < TOK; ++tk) acc[tk] = bias;
        const float* Wp = W_pair + (size_t)p * 512 * 256;
#pragma unroll 4
        for (int k = 0; k < 512; ++k) {
            const float w = Wp[(size_t)k * 256 + n];
            const int xoff = ((k < 256) ? fi : fj) * 256 + (k & 255);
#pragma unroll
            for (int tk = 0; tk < TOK; ++tk) acc[tk] += xs[tk][xoff] * w;
        }
#pragma unroll
        for (int tk = 0; tk < TOK; ++tk)
            hf[tk][p * 256 + n] = tanhf(acc[tk]);
    }
    __syncthreads();

    float acc[TOK];
    const float bf = b_final[n];
#pragma unroll
    for (int tk = 0; tk < TOK; ++tk) acc[tk] = bf;
#pragma unroll 4
    for (int k = 0; k < PAIRS * 256; ++k) {
        const float w = W_final[(size_t)k * 256 + n];
#pragma unroll
        for (int tk = 0; tk < TOK; ++tk) acc[tk] += hf[tk][k] * w;
    }
#pragma unroll
    for (int tk = 0; tk < TOK; ++tk)
        out[(size_t)(t0 + tk) * EMB + n] = acc[tk];
}

// ===========================================================================

extern "C" void kernel_launch(void* const* d_in, const int* in_sizes, int n_in,
                              void* d_out, int out_size, void* d_ws, size_t ws_size,
                              hipStream_t stream) {
    const float* feats   = (const float*)d_in[0];
    const float* W_pair  = (const float*)d_in[1];
    const float* b_pair  = (const float*)d_in[2];
    const float* W_final = (const float*)d_in[3];
    const float* b_final = (const float*)d_in[4];
    const int*   NAS     = (const int*)d_in[5];

    const size_t needed = ((size_t)PAIRS * 256 * 512 + (size_t)256 * 3840) * 2;

    if (ws_size >= needed) {
        u16* Wp_t = (u16*)d_ws;                         // 15*256*512 bf16
        u16* Wf_t = Wp_t + (size_t)PAIRS * 256 * 512;   // 256*3840 bf16
        transpose_cvt2<<<dim3(3840 / 32, 256 / 32, PAIRS + 1), 256, 0, stream>>>(
            W_pair, W_final, Wp_t, Wf_t);
        fused_cblock<<<BS / 64, 512, 0, stream>>>(feats, Wp_t, b_pair, Wf_t,
                                                  b_final, NAS, (float*)d_out);
    } else {
        fallback_cblock<<<BS / TOK, 256, 0, stream>>>(feats, W_pair, b_pair,
                                                      W_final, b_final, NAS,
                                                      (float*)d_out);
    }
}

// Round 10
// 176.494 us; speedup vs baseline: 1.0922x; 1.0189x over previous
//
#include <hip/hip_runtime.h>
#include <hip/hip_bf16.h>

// ---------------------------------------------------------------------------
// Hierarchical_CBlock: 15 pairwise GEMMs [16384x512]@[512x256] + bias + tanh
// + NAS mask, then final GEMM [16384x3840]@[3840x256] + bias.
// fp32 interfaces; bf16 internal MFMA (absmax 7.8e-3 vs 2.31e-2 threshold).
// History: R7 retile / R8+R13 occupancy / R9+R10 counted-vmcnt / R15 X-panels
//   => ALL neutral at ~1950 cyc/kstep. Unifying theory: weight-tile staging
//   is SOURCE-throughput-bound at 8.4 B/cyc/CU (L3 service), not latency-
//   bound: the 100MB once-read fp32 feature stream (zero cross-block reuse)
//   continuously evicts the ~1.2MB active weight set from each XCD's 4MB L2
//   (4MB features/XCD per pair-phase), so every CU's 16KB tile fetch pays
//   L3 rates. m97 proves the gload_lds path itself sustains >=22 B/cyc/CU.
// R16: cache-priority inversion (one axis, on the R15 base):
//   - feature panel loads -> __builtin_nontemporal_load (streaming, no L2
//     pollution; features are block-private, zero reuse)
//   - output stores -> __builtin_nontemporal_store (16MB once-written)
//   Weights stay L2-resident => tile fill at L2 rates (~22 B/cyc/CU).
// ---------------------------------------------------------------------------

typedef unsigned short u16;
typedef __bf16 bf16x8 __attribute__((ext_vector_type(8)));
typedef float f32x4 __attribute__((ext_vector_type(4)));

#define BS 16384      // B*S tokens
#define EMB 256
#define PAIRS 15
#define XR 264        // row stride (u16) for lds_x/lds_h: 528B rows, 16B-aligned

__constant__ int c_pi[PAIRS] = {0,0,0,0,0,1,1,1,1,2,2,2,3,3,4};
__constant__ int c_pj[PAIRS] = {1,2,3,4,5,2,3,4,5,3,4,5,4,5,5};

__device__ __forceinline__ u16 f2bf_u(float x) {
    __bf16 b = (__bf16)x;   // RTN
    return __builtin_bit_cast(u16, b);
}

// ============== merged transpose + fp32->bf16 convert ======================
__global__ __launch_bounds__(256) void transpose_cvt2(
    const float* __restrict__ Wp, const float* __restrict__ Wf,
    u16* __restrict__ Wp_t, u16* __restrict__ Wf_t)
{
    __shared__ float t[32][33];
    const int z = blockIdx.z;
    const float* in;
    u16* out;
    int R;
    if (z < PAIRS) { R = 512;  in = Wp + (size_t)z * 512 * 256; out = Wp_t + (size_t)z * 256 * 512; }
    else           { R = 3840; in = Wf;                          out = Wf_t; }
    const int r0 = blockIdx.x * 32;
    if (r0 >= R) return;                    // block-uniform early exit
    const int c0 = blockIdx.y * 32;
    const int tr = threadIdx.x >> 5;
    const int tc = threadIdx.x & 31;
#pragma unroll
    for (int pass = 0; pass < 4; ++pass)
        t[pass * 8 + tr][tc] = in[(size_t)(r0 + pass * 8 + tr) * 256 + c0 + tc];
    __syncthreads();
#pragma unroll
    for (int pass = 0; pass < 4; ++pass)
        out[(size_t)(c0 + pass * 8 + tr) * R + r0 + tc] = f2bf_u(t[tc][pass * 8 + tr]);
}

// ============================ fused MFMA path ==============================

// Stage a 32k x 256n bf16 weight tile (16 KB) into LDS as 1024 16B chunks.
__device__ __forceinline__ void stage_tile(const u16* gsrc, int row_stride_us,
                                           int col_off_us, u16* lds_base, int tid) {
    int wave = tid >> 6;
#pragma unroll
    for (int r = 0; r < 2; ++r) {
        int c  = r * 512 + tid;
        int n  = c & 255;
        int kb = c >> 8;
        const u16* g = gsrc + (size_t)n * row_stride_us + col_off_us + kb * 8;
        u16* l = lds_base + (size_t)(r * 512 + wave * 64) * 8;  // wave-uniform
        __builtin_amdgcn_global_load_lds(
            (const __attribute__((address_space(1))) void*)g,
            (__attribute__((address_space(3))) void*)l,
            16, 0, 0);
    }
}

// Load a whole 64x256 feature panel into 8 f32x4 regs — NON-TEMPORAL
// (features are block-private / once-read: keep them out of L2 so the
// 32-way-reused weight tiles stay resident).
__device__ __forceinline__ void xpanel_load(const float* fsrc, int t0,
                                            int xrow, int xcg, f32x4* xb) {
#pragma unroll
    for (int i = 0; i < 8; ++i)
        xb[i] = __builtin_nontemporal_load(
            (const f32x4*)(fsrc + (size_t)(t0 + xrow) * EMB + i * 32 + xcg));
}

// Convert + write the register panel into an LDS X panel (stride XR).
__device__ __forceinline__ void xpanel_write(const f32x4* xb, u16* ldsx,
                                             int xrow, int xcg) {
#pragma unroll
    for (int i = 0; i < 8; ++i) {
        ushort4 o;
        o.x = f2bf_u(xb[i][0]); o.y = f2bf_u(xb[i][1]);
        o.z = f2bf_u(xb[i][2]); o.w = f2bf_u(xb[i][3]);
        *(ushort4*)(&ldsx[xrow * XR + i * 32 + xcg]) = o;   // 8B store
    }
}

__global__ __launch_bounds__(512, 2) void fused_cblock(
    const float* __restrict__ feats,   // [6][16384][256] fp32
    const u16* __restrict__ Wp_t,      // [15][256][512] bf16 (transposed)
    const float* __restrict__ b_pair,  // [15][256] fp32
    const u16* __restrict__ Wf_t,      // [256][3840] bf16 (transposed)
    const float* __restrict__ b_final, // [256] fp32
    const int* __restrict__ NAS,       // [6]
    float* __restrict__ out)           // [16384][256] fp32
{
    __shared__ u16 lds_b[2][8192];     // 2 x 16KB weight-tile double buffer
    __shared__ u16 lds_xA[64 * XR];    // X panel (fi / next fi), 33KB
    __shared__ u16 lds_xB[64 * XR];    // X panel (fj), 33KB
    __shared__ u16 lds_h[64 * XR];     // h tile bf16, 33KB

    const int tid  = threadIdx.x;
    const int lane = tid & 63;
    const int wave = tid >> 6;
    const int wm   = wave & 1;         // 32-token slab
    const int wn   = wave >> 1;        // 64-col group (0..3)
    const int quad = lane >> 4;
    const int l16  = lane & 15;
    const int t0   = blockIdx.x * 64;
    const int xrow = tid >> 3;         // panel row (0..63)
    const int xcg  = (tid & 7) * 4;    // panel col group

    int nasv[6];
#pragma unroll
    for (int f = 0; f < 6; ++f) nasv[f] = (f < 2) ? 1 : (NAS[f] != 0 ? 1 : 0);
    int pmask = 0;
#pragma unroll
    for (int p = 0; p < PAIRS; ++p)
        if (nasv[c_pi[p]] & nasv[c_pj[p]]) pmask |= (1 << p);
    // pair 0 always active (features 0,1 forced on) => pmask bit0 == 1, fi=0.

    // ---- prologue: feature-0 panel -> xA, Wp0 k0 tile -> b0 ---------------
    f32x4 xb[8];
    xpanel_load(feats, t0, xrow, xcg, xb);
    stage_tile(Wp_t, 512, 0, lds_b[0], tid);
    xpanel_write(xb, lds_xA, xrow, xcg);    // auto-wait retires panel loads
    __syncthreads();                         // tile0 + xA ready

    const f32x4 fzero = {0.f, 0.f, 0.f, 0.f};
    f32x4 acc2[8];
#pragma unroll
    for (int i = 0; i < 8; ++i) acc2[i] = fzero;

    for (int p = 0; p < PAIRS; ++p) {
        if (!((pmask >> p) & 1)) continue;          // block-uniform
        const int fj = c_pj[p];
        const u16* WpT = Wp_t + (size_t)p * 256 * 512;
        const int rest  = pmask >> (p + 1);
        const int pnext = rest ? (p + 1 + __builtin_ctz(rest)) : -1;

        // -------- GEMM1: h[64x256] = tanh(X[64x512] @ Wp + b) --------------
        // Preconditions: lds_b[0] = Wp_p k0; lds_xA = X(fi) panel.
        f32x4 acc1[8];
#pragma unroll
        for (int i = 0; i < 8; ++i) acc1[i] = fzero;

        for (int ks = 0; ks < 16; ++ks) {
            const int cur = ks & 1;
            if (ks == 0)   // fj panel regs: ~7 ksteps of cover before write
                xpanel_load(feats + (size_t)fj * BS * EMB, t0, xrow, xcg, xb);
            if (ks < 15)
                stage_tile(WpT, 512, (ks + 1) * 32, lds_b[1 - cur], tid);
            else
                stage_tile(Wf_t, 3840, p * 256, lds_b[1 - cur], tid); // GEMM2 k0
            const u16* xs = (ks < 8) ? lds_xA : lds_xB;
            const int ko = (ks & 7) * 32 + quad * 8;
            bf16x8 a0 = *(const bf16x8*)(&xs[(wm * 32 + l16) * XR + ko]);
            bf16x8 a1 = *(const bf16x8*)(&xs[(wm * 32 + 16 + l16) * XR + ko]);
#pragma unroll
            for (int nt = 0; nt < 4; ++nt) {
                const int n = wn * 64 + nt * 16 + l16;
                bf16x8 b = *(const bf16x8*)(&lds_b[cur][(quad * 256 + n) * 8]);
                acc1[nt]     = __builtin_amdgcn_mfma_f32_16x16x32_bf16(a0, b, acc1[nt],     0, 0, 0);
                acc1[4 + nt] = __builtin_amdgcn_mfma_f32_16x16x32_bf16(a1, b, acc1[4 + nt], 0, 0, 0);
            }
            if (ks == 7)   // publish fj panel (reads of xB start at ks=8,
                xpanel_write(xb, lds_xB, xrow, xcg);  // after this barrier)
            __syncthreads();
        }

        // tanh + bias (fp32), h -> LDS bf16
#pragma unroll
        for (int mt = 0; mt < 2; ++mt)
#pragma unroll
        for (int nt = 0; nt < 4; ++nt) {
            const int n = wn * 64 + nt * 16 + l16;
            const float bias = b_pair[p * 256 + n];
#pragma unroll
            for (int r = 0; r < 4; ++r) {
                const int row = wm * 32 + mt * 16 + quad * 4 + r;  // C/D: row=quad*4+reg
                lds_h[row * XR + n] = f2bf_u(tanhf(acc1[mt * 4 + nt][r] + bias));
            }
        }
        __syncthreads();   // publish lds_h (Wf k0 drained at ks=15 barrier)

        // -------- GEMM2: acc2 += h[64x256] @ Wf_p[256x256] ------------------
        for (int ks = 0; ks < 8; ++ks) {
            const int cur = ks & 1;
            if (ks == 0 && pnext >= 0)   // next pair's fi panel into regs
                xpanel_load(feats + (size_t)c_pi[pnext] * BS * EMB, t0, xrow, xcg, xb);
            if (ks < 7)
                stage_tile(Wf_t, 3840, p * 256 + (ks + 1) * 32, lds_b[1 - cur], tid);
            else   // next pair's Wp k0 (dummy reload when last pair)
                stage_tile(Wp_t + (size_t)((pnext >= 0) ? pnext : p) * 256 * 512,
                           512, 0, lds_b[1 - cur], tid);
            const int e0 = ks * 32 + quad * 8;
            bf16x8 a0 = *(const bf16x8*)(&lds_h[(wm * 32 + l16) * XR + e0]);
            bf16x8 a1 = *(const bf16x8*)(&lds_h[(wm * 32 + 16 + l16) * XR + e0]);
#pragma unroll
            for (int nt = 0; nt < 4; ++nt) {
                const int n = wn * 64 + nt * 16 + l16;
                bf16x8 b = *(const bf16x8*)(&lds_b[cur][(quad * 256 + n) * 8]);
                acc2[nt]     = __builtin_amdgcn_mfma_f32_16x16x32_bf16(a0, b, acc2[nt],     0, 0, 0);
                acc2[4 + nt] = __builtin_amdgcn_mfma_f32_16x16x32_bf16(a1, b, acc2[4 + nt], 0, 0, 0);
            }
            if (ks == 7 && pnext >= 0)   // publish next fi panel into xA
                xpanel_write(xb, lds_xA, xrow, xcg);  // (xA reads resume next
            __syncthreads();                           //  pair G1 ks=0)
        }
    }

    // epilogue: + b_final, NON-TEMPORAL fp32 store (once-written stream)
#pragma unroll
    for (int mt = 0; mt < 2; ++mt)
#pragma unroll
    for (int nt = 0; nt < 4; ++nt) {
        const int n = wn * 64 + nt * 16 + l16;
        const float bf = b_final[n];
#pragma unroll
        for (int r = 0; r < 4; ++r) {
            const int t = t0 + wm * 32 + mt * 16 + quad * 4 + r;
            __builtin_nontemporal_store(acc2[mt * 4 + nt][r] + bf,
                                        &out[(size_t)t * EMB + n]);
        }
    }
}

// ================== exact fp32 VALU fallback (ws-free) =====================

#define TOK 4

__global__ __launch_bounds__(256) void fallback_cblock(
    const float* __restrict__ feats, const float* __restrict__ W_pair,
    const float* __restrict__ b_pair, const float* __restrict__ W_final,
    const float* __restrict__ b_final, const int* __restrict__ NAS,
    float* __restrict__ out)
{
    __shared__ float xs[TOK][6 * 256];
    __shared__ float hf[TOK][PAIRS * 256];

    const int n  = threadIdx.x;
    const int t0 = blockIdx.x * TOK;

#pragma unroll
    for (int tk = 0; tk < TOK; ++tk)
#pragma unroll
        for (int f = 0; f < 6; ++f)
            xs[tk][f * 256 + n] = feats[((size_t)f * BS + t0 + tk) * EMB + n];
    __syncthreads();

    int nasv[6];
#pragma unroll
    for (int f = 0; f < 6; ++f) nasv[f] = (f < 2) ? 1 : (NAS[f] != 0 ? 1 : 0);

    for (int p = 0; p < PAIRS; ++p) {
        const int fi = c_pi[p], fj = c_pj[p];
        if (!(nasv[fi] & nasv[fj])) {
#pragma unroll
            for (int tk = 0; tk < TOK; ++tk) hf[tk][p * 256 + n] = 0.f;
            continue;
        }
        float acc[TOK];
        const float bias = b_pair[p * 256 + n];
#pragma unroll
        for (int tk = 0; tk < TOK; ++tk) acc[tk] = bias;
        const float* Wp = W_pair + (size_t)p * 512 * 256;
#pragma unroll 4
        for (int k = 0; k < 512; ++k) {
            const float w = Wp[(size_t)k * 256 + n];
            const int xoff = ((k < 256) ? fi : fj) * 256 + (k & 255);
#pragma unroll
            for (int tk = 0; tk < TOK; ++tk) acc[tk] += xs[tk][xoff] * w;
        }
#pragma unroll
        for (int tk = 0; tk < TOK; ++tk)
            hf[tk][p * 256 + n] = tanhf(acc[tk]);
    }
    __syncthreads();

    float acc[TOK];
    const float bf = b_final[n];
#pragma unroll
    for (int tk = 0; tk < TOK; ++tk) acc[tk] = bf;
#pragma unroll 4
    for (int k = 0; k < PAIRS * 256; ++k) {
        const float w = W_final[(size_t)k * 256 + n];
#pragma unroll
        for (int tk = 0; tk < TOK; ++tk) acc[tk] += hf[tk][k] * w;
    }
#pragma unroll
    for (int tk = 0; tk < TOK; ++tk)
        out[(size_t)(t0 + tk) * EMB + n] = acc[tk];
}

// ===========================================================================

extern "C" void kernel_launch(void* const* d_in, const int* in_sizes, int n_in,
                              void* d_out, int out_size, void* d_ws, size_t ws_size,
                              hipStream_t stream) {
    const float* feats   = (const float*)d_in[0];
    const float* W_pair  = (const float*)d_in[1];
    const float* b_pair  = (const float*)d_in[2];
    const float* W_final = (const float*)d_in[3];
    const float* b_final = (const float*)d_in[4];
    const int*   NAS     = (const int*)d_in[5];

    const size_t needed = ((size_t)PAIRS * 256 * 512 + (size_t)256 * 3840) * 2;

    if (ws_size >= needed) {
        u16* Wp_t = (u16*)d_ws;                         // 15*256*512 bf16
        u16* Wf_t = Wp_t + (size_t)PAIRS * 256 * 512;   // 256*3840 bf16
        transpose_cvt2<<<dim3(3840 / 32, 256 / 32, PAIRS + 1), 256, 0, stream>>>(
            W_pair, W_final, Wp_t, Wf_t);
        fused_cblock<<<BS / 64, 512, 0, stream>>>(feats, Wp_t, b_pair, Wf_t,
                                                  b_final, NAS, (float*)d_out);
    } else {
        fallback_cblock<<<BS / TOK, 256, 0, stream>>>(feats, W_pair, b_pair,
                                                      W_final, b_final, NAS,
                                                      (float*)d_out);
    }
}